// Round 9
// baseline (1698.371 us; speedup 1.0000x reference)
//
#include <hip/hip_runtime.h>
#include <hip/hip_fp16.h>
#include <cstdint>
#include <cstddef>

#define KKSLOTS 25

typedef __attribute__((ext_vector_type(8))) short short8;
typedef __attribute__((ext_vector_type(4))) float f32x4;
typedef __attribute__((ext_vector_type(4))) unsigned short us4;

__device__ __forceinline__ unsigned short f2bf(float f) {
    unsigned u = __float_as_uint(f);
    u += 0x7FFF + ((u >> 16) & 1);           // RNE
    return (unsigned short)(u >> 16);
}
__device__ __forceinline__ float bf2f(unsigned short b) {
    return __uint_as_float((unsigned)b << 16);
}
__device__ __forceinline__ unsigned pack_h2(float a, float b) {
    unsigned short ha = __half_as_ushort(__float2half_rn(a));
    unsigned short hb = __half_as_ushort(__float2half_rn(b));
    return (unsigned)ha | ((unsigned)hb << 16);
}
__device__ __forceinline__ float h2f(unsigned short u) {
    return __half2float(__ushort_as_half(u));
}

// ===========================================================================
// CSR build: counting sort of edges by dst, with precomputed spline records.
// Record (int4): {src, packed_slots(4x5bit), half2(w00,w01), half2(w10,w11)}
// ===========================================================================
__global__ void csr_count_kernel(const int* __restrict__ dst, int* __restrict__ cnt, int E) {
    int e = blockIdx.x * blockDim.x + threadIdx.x;
    if (e < E) atomicAdd(&cnt[dst[e]], 1);
}

#define SCAN_B 256
__global__ __launch_bounds__(SCAN_B) void scan1_kernel(const int* __restrict__ cnt,
                                                       int* __restrict__ off,
                                                       int* __restrict__ bsum, int N) {
    __shared__ int tmp[SCAN_B];
    int g = blockIdx.x * SCAN_B + threadIdx.x;
    int v = (g < N) ? cnt[g] : 0;
    tmp[threadIdx.x] = v;
    __syncthreads();
    for (int d = 1; d < SCAN_B; d <<= 1) {
        int t = (threadIdx.x >= d) ? tmp[threadIdx.x - d] : 0;
        __syncthreads();
        tmp[threadIdx.x] += t;
        __syncthreads();
    }
    if (g < N) off[g] = tmp[threadIdx.x] - v;      // exclusive
    if (threadIdx.x == SCAN_B - 1) bsum[blockIdx.x] = tmp[threadIdx.x];
}

__global__ __launch_bounds__(SCAN_B) void scan2_kernel(int* __restrict__ bsum, int nb) {
    __shared__ int tmp[SCAN_B];
    int v = (threadIdx.x < nb) ? bsum[threadIdx.x] : 0;
    tmp[threadIdx.x] = v;
    __syncthreads();
    for (int d = 1; d < SCAN_B; d <<= 1) {
        int t = (threadIdx.x >= d) ? tmp[threadIdx.x - d] : 0;
        __syncthreads();
        tmp[threadIdx.x] += t;
        __syncthreads();
    }
    if (threadIdx.x < nb) bsum[threadIdx.x] = tmp[threadIdx.x] - v;  // exclusive
}

__global__ void scan3_kernel(int* __restrict__ off, const int* __restrict__ bsum, int N) {
    int g = blockIdx.x * SCAN_B + threadIdx.x;
    if (g < N) off[g] += bsum[blockIdx.x];
}

// After this kernel: off[n] == end(n); start(n) = (n==0) ? 0 : off[n-1].
__global__ void csr_fill_kernel(const int* __restrict__ src, const int* __restrict__ dst,
                                const float* __restrict__ pseudo,
                                int* __restrict__ off, int4* __restrict__ rec, int E) {
    int e = blockIdx.x * blockDim.x + threadIdx.x;
    if (e >= E) return;
    int d = dst[e];
    int p = atomicAdd(&off[d], 1);
    float v0 = pseudo[2 * e + 0] * 4.0f;
    float v1 = pseudo[2 * e + 1] * 4.0f;
    float fl0 = floorf(v0), fl1 = floorf(v1);
    float f0 = v0 - fl0, f1 = v1 - fl1;
    int b0 = (int)fl0, b1 = (int)fl1;
    int i0a = min(max(b0, 0), 4),     i1a = min(max(b1, 0), 4);
    int i0b = min(max(b0 + 1, 0), 4), i1b = min(max(b1 + 1, 0), 4);
    int s00 = i0a * 5 + i1a;   // corner 0: (1-f0)(1-f1)
    int s01 = i0a * 5 + i1b;   // corner 1: (1-f0)f1
    int s10 = i0b * 5 + i1a;   // corner 2: f0(1-f1)
    int s11 = i0b * 5 + i1b;   // corner 3: f0 f1
    float g0 = 1.0f - f0, g1 = 1.0f - f1;
    int4 r;
    r.x = src[e];
    r.y = s00 | (s01 << 5) | (s10 << 10) | (s11 << 15);
    r.z = (int)pack_h2(g0 * g1, g0 * f1);
    r.w = (int)pack_h2(f0 * g1, f0 * f1);
    rec[p] = r;
}

// ===========================================================================
// fp32 -> bf16 elementwise
// ===========================================================================
__global__ void to_bf16_kernel(const float* __restrict__ in, unsigned short* __restrict__ out, int n) {
    int i = blockIdx.x * 256 + threadIdx.x;
    if (i < n) out[i] = f2bf(in[i]);
}

// ===========================================================================
// build WT[OP][KP] bf16 = transpose of [W ; root] padded with zeros.
// ===========================================================================
template<int KP, int I, int O, int OP>
__global__ void build_wt_kernel(const float* __restrict__ W, const float* __restrict__ root,
                                unsigned short* __restrict__ WT) {
    int idx = blockIdx.x * 256 + threadIdx.x;
    if (idx >= OP * KP) return;
    int o = idx / KP, k = idx - o * KP;
    float v = 0.0f;
    if (o < O) {
        if (k < KKSLOTS * I) v = W[(size_t)k * O + o];
        else if (k < (KKSLOTS + 1) * I) v = root[(size_t)(k - KKSLOTS * I) * O + o];
    }
    WT[idx] = f2bf(v);
}

// ===========================================================================
// segmented accumulation over dst-sorted edges, NODE-ALIGNED wave ranges.
// Wave-private LDS tile [25][I]; lane = (edge_sub h, channel); EPW = 64/I
// edges in flight. Accumulation via FIRE-AND-FORGET ds_add_f32 (no-return
// LDS atomic): no read-modify-write chain, no lgkmcnt stalls, and multiple
// concurrent edges into the same tile are race-free.
// Flush per node: row = [bf16(acc * 1/deg) | hin | zeros], packed b32 stores.
// ===========================================================================
template<int I, int KP>
__global__ __launch_bounds__(256) void seg_accum_kernel(
        const unsigned short* __restrict__ xb, const int4* __restrict__ rec,
        const int* __restrict__ off, unsigned short* __restrict__ accB,
        int nlo, int nhi) {
    constexpr int SLOTS = KKSLOTS * I;
    constexpr int EPW = 64 / I;
    __shared__ float la_all[4][SLOTS];
    int wline = threadIdx.x >> 6, lane = threadIdx.x & 63;
    float* la = la_all[wline];
    int wid = blockIdx.x * 4 + wline;
    int nwt = gridDim.x << 2;

    int e_lo = (nlo == 0) ? 0 : off[nlo - 1];
    int e_hi = off[nhi - 1];
    long long span = (long long)e_hi - e_lo;
    int t0 = e_lo + (int)(span * wid / nwt);
    int t1 = e_lo + (int)(span * (wid + 1) / nwt);

    int ns, ne;
    {   int lo = nlo, hi = nhi;
        while (lo < hi) { int m = (lo + hi) >> 1; if (off[m] > t0) hi = m; else lo = m + 1; }
        ns = (wid == 0) ? nlo : lo; }
    {   int lo = nlo, hi = nhi;
        while (lo < hi) { int m = (lo + hi) >> 1; if (off[m] > t1) hi = m; else lo = m + 1; }
        ne = (wid == nwt - 1) ? nhi : lo; }
    if (ns >= ne) return;

    int h  = lane / I;            // edge sub-index within wave
    int ch = lane % I;            // channel

    for (int t = lane; t < SLOTS; t += 64) la[t] = 0.0f;

    int j = (ns == 0) ? 0 : off[ns - 1];
    for (int n = ns; n < ne; ++n) {
        int je = off[n];
        int jstart = j;
        for (; j < je; j += EPW) {
            int idx = j + h;
            int cl = min(idx, je - 1);
            int4 r = rec[cl];
            float scale = (idx < je) ? 1.0f : 0.0f;
            float xv = bf2f(xb[(size_t)r.x * I + ch]) * scale;
            unsigned wz = (unsigned)r.z, ww = (unsigned)r.w;
            unsigned pk = (unsigned)r.y;
            unsafeAtomicAdd(&la[((pk      ) & 31) * I + ch], h2f((unsigned short)(wz & 0xFFFF)) * xv);
            unsafeAtomicAdd(&la[((pk >> 5 ) & 31) * I + ch], h2f((unsigned short)(wz >> 16))    * xv);
            unsafeAtomicAdd(&la[((pk >> 10) & 31) * I + ch], h2f((unsigned short)(ww & 0xFFFF)) * xv);
            unsafeAtomicAdd(&la[((pk >> 15) & 31) * I + ch], h2f((unsigned short)(ww >> 16))    * xv);
        }
        j = je;

        // flush node n
        float dinv = 1.0f / fmaxf((float)(je - jstart), 1.0f);
        unsigned* drow = (unsigned*)(accB + (size_t)(n - nlo) * KP);
        const unsigned* hrow = (const unsigned*)(xb + (size_t)n * I);
        for (int t = lane; t < KP / 2; t += 64) {
            int e0 = 2 * t;
            unsigned outv;
            if (e0 < SLOTS) {
                float v0 = la[e0] * dinv, v1 = la[e0 + 1] * dinv;
                outv = (unsigned)f2bf(v0) | ((unsigned)f2bf(v1) << 16);
            } else {
                int ii = e0 - SLOTS;
                outv = (ii < I) ? hrow[ii >> 1] : 0u;
            }
            drow[t] = outv;
        }
        for (int t = lane; t < SLOTS; t += 64) la[t] = 0.0f;
    }
}

// ===========================================================================
// MFMA contraction, LDS-free: hout[n][o] = ELU( accB[n][:].WT[o][:] + bias[o] )
// Block = 64 nodes x OP outputs; wave = 16 nodes. Both A and B fragments are
// direct 16B global loads (WT is k-contiguous and L2-resident); no barriers.
// mfma_f32_16x16x32_bf16; C/D: col(l16)=o, row(quad*4+reg)=node.
// ===========================================================================
template<int KP, int O, int OP>
__global__ __launch_bounds__(256) void contract_mfma_kernel(
        const unsigned short* __restrict__ accB, const unsigned short* __restrict__ WT,
        const float* __restrict__ bias, unsigned short* __restrict__ hout,
        int nlo, int nhi) {
    constexpr int NF = OP / 16;
    int tid = threadIdx.x;
    int wv = tid >> 6, lane = tid & 63;
    int quad = lane >> 4, l16 = lane & 15;
    int n0 = nlo + blockIdx.x * 64;

    int an = n0 + wv * 16 + l16;
    int arow = min(an, nhi - 1) - nlo;
    const unsigned short* Ap = accB + (size_t)arow * KP + quad * 8;

    const unsigned short* Bp[NF];
    #pragma unroll
    for (int t = 0; t < NF; ++t)
        Bp[t] = WT + (size_t)(t * 16 + l16) * KP + quad * 8;

    f32x4 acc[NF];
    #pragma unroll
    for (int t = 0; t < NF; ++t) acc[t] = (f32x4){0.0f, 0.0f, 0.0f, 0.0f};

    for (int k0 = 0; k0 < KP; k0 += 32) {
        short8 a = *(const short8*)(Ap + k0);
        #pragma unroll
        for (int t = 0; t < NF; ++t) {
            short8 b = *(const short8*)(Bp[t] + k0);
            acc[t] = __builtin_amdgcn_mfma_f32_16x16x32_bf16(a, b, acc[t], 0, 0, 0);
        }
    }

    #pragma unroll
    for (int t = 0; t < NF; ++t) {
        int o = t * 16 + l16;
        if (o >= O) continue;
        float bs = bias[o];
        #pragma unroll
        for (int r = 0; r < 4; ++r) {
            int n = n0 + wv * 16 + quad * 4 + r;
            if (n >= nhi) continue;
            float v = acc[t][r] + bs;
            v = (v > 0.0f) ? v : expm1f(v);
            hout[(size_t)n * O + o] = f2bf(v);
        }
    }
}

// ===========================================================================
// segmented graph sum (batch sorted, h3 bf16) + fused count + head
// ===========================================================================
#define GS_CH 128
__global__ __launch_bounds__(128) void graph_reduce_kernel(
        const unsigned short* __restrict__ h3, const int* __restrict__ batch,
        float* __restrict__ g, float* __restrict__ cnt, int N) {
    int o = threadIdx.x;
    int n0 = blockIdx.x * GS_CH;
    int n1 = min(n0 + GS_CH, N);
    if (o < 124) {
        float local = 0.0f;
        int cur_b = batch[n0];
        for (int n = n0; n < n1; ++n) {
            int b = batch[n];
            if (b != cur_b) {
                atomicAdd(&g[cur_b * 124 + o], local);
                local = 0.0f;
                cur_b = b;
            }
            local += bf2f(h3[(size_t)n * 124 + o]);
        }
        atomicAdd(&g[cur_b * 124 + o], local);
    } else if (o == 124) {
        float localc = 0.0f;
        int cur_b = batch[n0];
        for (int n = n0; n < n1; ++n) {
            int b = batch[n];
            if (b != cur_b) {
                atomicAdd(&cnt[cur_b], localc);
                localc = 0.0f;
                cur_b = b;
            }
            localc += 1.0f;
        }
        atomicAdd(&cnt[cur_b], localc);
    }
}

__global__ void head_kernel(const float* __restrict__ g, const float* __restrict__ cnt,
                            const float* __restrict__ fcw, const float* __restrict__ fcb,
                            float* __restrict__ out) {
    __shared__ float logits[32];
    __shared__ float red[2];
    int b = blockIdx.x;
    int o = threadIdx.x;
    float c = fmaxf(cnt[b], 1.0f);
    if (o < 30) {
        float a = fcb[o];
        for (int i = 0; i < 124; ++i)
            a = fmaf(g[b * 124 + i] / c, fcw[i * 30 + o], a);
        logits[o] = a;
    }
    __syncthreads();
    if (o == 0) {
        float m = -1e30f;
        for (int j = 0; j < 30; ++j) m = fmaxf(m, logits[j]);
        float s = 0.0f;
        for (int j = 0; j < 30; ++j) s += expf(logits[j] - m);
        red[0] = m;
        red[1] = logf(s);
    }
    __syncthreads();
    if (o < 30) out[b * 30 + o] = logits[o] - red[0] - red[1];
}

// ---------------------------------------------------------------------------
// per-layer driver (node-chunked so acc fits whatever ws_size allows)
// ---------------------------------------------------------------------------
template<int I, int O, int OP>
static void run_layer(const unsigned short* hb, const unsigned short* WT, const float* bias,
                      unsigned short* hout, unsigned short* accB,
                      const int4* rec, const int* off,
                      int N, size_t avail, hipStream_t stream) {
    constexpr int KP = ((26 * I + 31) / 32) * 32;
    size_t perNode = (size_t)KP * 2;
    size_t maxNodesS = avail / perNode;
    int maxNodes = (maxNodesS > (size_t)N) ? N : (int)maxNodesS;
    if (maxNodes < 64) maxNodes = 64;
    for (int nlo = 0; nlo < N; nlo += maxNodes) {
        int nhi = nlo + maxNodes;
        if (nhi > N) nhi = N;
        int cn = nhi - nlo;
        seg_accum_kernel<I, KP><<<2048, 256, 0, stream>>>(hb, rec, off, accB, nlo, nhi);
        contract_mfma_kernel<KP, O, OP><<<(cn + 63) / 64, 256, 0, stream>>>(
            accB, WT, bias, hout, nlo, nhi);
    }
}

extern "C" void kernel_launch(void* const* d_in, const int* in_sizes, int n_in,
                              void* d_out, int out_size, void* d_ws, size_t ws_size,
                              hipStream_t stream) {
    const float* x      = (const float*)d_in[0];
    const int*   ei     = (const int*)  d_in[1];
    const float* pseudo = (const float*)d_in[2];
    const int*   batch  = (const int*)  d_in[3];
    const float* W1 = (const float*)d_in[4];
    const float* r1 = (const float*)d_in[5];
    const float* b1 = (const float*)d_in[6];
    const float* W2 = (const float*)d_in[7];
    const float* r2 = (const float*)d_in[8];
    const float* b2 = (const float*)d_in[9];
    const float* W3 = (const float*)d_in[10];
    const float* r3 = (const float*)d_in[11];
    const float* b3 = (const float*)d_in[12];
    const float* fcw = (const float*)d_in[13];
    const float* fcb = (const float*)d_in[14];

    int N = in_sizes[0] / 8;
    int E = in_sizes[1] / 2;
    const int* srcp = ei;
    const int* dstp = ei + E;

    constexpr int KP1 = 224, KP2 = 832, KP3 = 1664;

    // workspace carve (all pieces 16B-multiple)
    char* p = (char*)d_ws;
    unsigned short* xb  = (unsigned short*)p; p += (size_t)N * 8 * 2;
    unsigned short* h1  = (unsigned short*)p; p += (size_t)N * 32 * 2;
    unsigned short* h2  = (unsigned short*)p; p += (size_t)N * 64 * 2;
    unsigned short* h3  = (unsigned short*)p; p += (size_t)N * 124 * 2;
    float* gbuf = (float*)p; p += 64 * 124 * 4;
    float* cntF = (float*)p; p += 256;
    int*   cntI = (int*)p;   p += ((size_t)N * 4 + 15) & ~15ULL;
    int*   off  = (int*)p;   p += ((size_t)N * 4 + 15) & ~15ULL;
    int*   bsum = (int*)p;   p += SCAN_B * 4;
    int4*  rec  = (int4*)p;  p += (size_t)E * 16;
    unsigned short* WT1 = (unsigned short*)p; p += (size_t)32  * KP1 * 2;
    unsigned short* WT2 = (unsigned short*)p; p += (size_t)64  * KP2 * 2;
    unsigned short* WT3 = (unsigned short*)p; p += (size_t)128 * KP3 * 2;
    unsigned short* accB = (unsigned short*)p;
    size_t used = (size_t)(p - (char*)d_ws);
    size_t avail = (ws_size > used) ? (ws_size - used) : 0;

    // zero: gbuf + cntF + cntI (contiguous)
    hipMemsetAsync(gbuf, 0, 64 * 124 * 4 + 256 + (((size_t)N * 4 + 15) & ~15ULL), stream);

    // CSR build
    int nb_scan = (N + SCAN_B - 1) / SCAN_B;
    csr_count_kernel<<<(E + 255) / 256, 256, 0, stream>>>(dstp, cntI, E);
    scan1_kernel<<<nb_scan, SCAN_B, 0, stream>>>(cntI, off, bsum, N);
    scan2_kernel<<<1, SCAN_B, 0, stream>>>(bsum, nb_scan);
    scan3_kernel<<<nb_scan, SCAN_B, 0, stream>>>(off, bsum, N);
    csr_fill_kernel<<<(E + 255) / 256, 256, 0, stream>>>(srcp, dstp, pseudo, off, rec, E);

    // conversions / weight prep
    to_bf16_kernel<<<(N * 8 + 255) / 256, 256, 0, stream>>>(x, xb, N * 8);
    build_wt_kernel<KP1, 8,  32,  32 ><<<(32  * KP1 + 255) / 256, 256, 0, stream>>>(W1, r1, WT1);
    build_wt_kernel<KP2, 32, 64,  64 ><<<(64  * KP2 + 255) / 256, 256, 0, stream>>>(W2, r2, WT2);
    build_wt_kernel<KP3, 64, 124, 128><<<(128 * KP3 + 255) / 256, 256, 0, stream>>>(W3, r3, WT3);

    run_layer<8,  32,  32 >(xb, WT1, b1, h1, accB, rec, off, N, avail, stream);
    run_layer<32, 64,  64 >(h1, WT2, b2, h2, accB, rec, off, N, avail, stream);
    run_layer<64, 124, 128>(h2, WT3, b3, h3, accB, rec, off, N, avail, stream);

    graph_reduce_kernel<<<(N + GS_CH - 1) / GS_CH, 128, 0, stream>>>(h3, batch, gbuf, cntF, N);
    head_kernel<<<64, 64, 0, stream>>>(gbuf, cntF, fcw, fcb, (float*)d_out);
}

// Round 10
// 538.502 us; speedup vs baseline: 3.1539x; 3.1539x over previous
//
#include <hip/hip_runtime.h>
#include <cstdint>
#include <cstddef>

#define KKSLOTS 25

typedef __attribute__((ext_vector_type(8))) short short8;
typedef __attribute__((ext_vector_type(4))) float f32x4;
typedef __attribute__((ext_vector_type(4))) unsigned short us4;

__device__ __forceinline__ unsigned short f2bf(float f) {
    unsigned u = __float_as_uint(f);
    u += 0x7FFF + ((u >> 16) & 1);           // RNE
    return (unsigned short)(u >> 16);
}
__device__ __forceinline__ float bf2f(unsigned short b) {
    return __uint_as_float((unsigned)b << 16);
}

// ===========================================================================
// CSR build: counting sort of edges by dst, with precomputed spline records.
// Record (int4): {src, i0 | (i1<<8), bits(f0), bits(f1)}
// (pseudo in [0,1) => the 4 corners are rows {i0,i0+1} x cols {i1,i1+1})
// ===========================================================================
__global__ void csr_count_kernel(const int* __restrict__ dst, int* __restrict__ cnt, int E) {
    int e = blockIdx.x * blockDim.x + threadIdx.x;
    if (e < E) atomicAdd(&cnt[dst[e]], 1);
}

#define SCAN_B 256
__global__ __launch_bounds__(SCAN_B) void scan1_kernel(const int* __restrict__ cnt,
                                                       int* __restrict__ off,
                                                       int* __restrict__ bsum, int N) {
    __shared__ int tmp[SCAN_B];
    int g = blockIdx.x * SCAN_B + threadIdx.x;
    int v = (g < N) ? cnt[g] : 0;
    tmp[threadIdx.x] = v;
    __syncthreads();
    for (int d = 1; d < SCAN_B; d <<= 1) {
        int t = (threadIdx.x >= d) ? tmp[threadIdx.x - d] : 0;
        __syncthreads();
        tmp[threadIdx.x] += t;
        __syncthreads();
    }
    if (g < N) off[g] = tmp[threadIdx.x] - v;      // exclusive
    if (threadIdx.x == SCAN_B - 1) bsum[blockIdx.x] = tmp[threadIdx.x];
}

__global__ __launch_bounds__(SCAN_B) void scan2_kernel(int* __restrict__ bsum, int nb) {
    __shared__ int tmp[SCAN_B];
    int v = (threadIdx.x < nb) ? bsum[threadIdx.x] : 0;
    tmp[threadIdx.x] = v;
    __syncthreads();
    for (int d = 1; d < SCAN_B; d <<= 1) {
        int t = (threadIdx.x >= d) ? tmp[threadIdx.x - d] : 0;
        __syncthreads();
        tmp[threadIdx.x] += t;
        __syncthreads();
    }
    if (threadIdx.x < nb) bsum[threadIdx.x] = tmp[threadIdx.x] - v;  // exclusive
}

__global__ void scan3_kernel(int* __restrict__ off, const int* __restrict__ bsum, int N) {
    int g = blockIdx.x * SCAN_B + threadIdx.x;
    if (g < N) off[g] += bsum[blockIdx.x];
}

// After this kernel: off[n] == end(n); start(n) = (n==0) ? 0 : off[n-1].
__global__ void csr_fill_kernel(const int* __restrict__ src, const int* __restrict__ dst,
                                const float* __restrict__ pseudo,
                                int* __restrict__ off, int4* __restrict__ rec, int E) {
    int e = blockIdx.x * blockDim.x + threadIdx.x;
    if (e >= E) return;
    int d = dst[e];
    int p = atomicAdd(&off[d], 1);
    float v0 = pseudo[2 * e + 0] * 4.0f;
    float v1 = pseudo[2 * e + 1] * 4.0f;
    float fl0 = floorf(v0), fl1 = floorf(v1);
    float f0 = v0 - fl0, f1 = v1 - fl1;
    int i0 = min(max((int)fl0, 0), 3);
    int i1 = min(max((int)fl1, 0), 3);
    int4 r;
    r.x = src[e];
    r.y = i0 | (i1 << 8);
    r.z = __float_as_int(f0);
    r.w = __float_as_int(f1);
    rec[p] = r;
}

// ===========================================================================
// fp32 -> bf16 elementwise
// ===========================================================================
__global__ void to_bf16_kernel(const float* __restrict__ in, unsigned short* __restrict__ out, int n) {
    int i = blockIdx.x * 256 + threadIdx.x;
    if (i < n) out[i] = f2bf(in[i]);
}

// ===========================================================================
// build WT[OP][KP] bf16 = transpose of [W ; root] padded with zeros.
// ===========================================================================
template<int KP, int I, int O, int OP>
__global__ void build_wt_kernel(const float* __restrict__ W, const float* __restrict__ root,
                                unsigned short* __restrict__ WT) {
    int idx = blockIdx.x * 256 + threadIdx.x;
    if (idx >= OP * KP) return;
    int o = idx / KP, k = idx - o * KP;
    float v = 0.0f;
    if (o < O) {
        if (k < KKSLOTS * I) v = W[(size_t)k * O + o];
        else if (k < (KKSLOTS + 1) * I) v = root[(size_t)(k - KKSLOTS * I) * O + o];
    }
    WT[idx] = f2bf(v);
}

// ===========================================================================
// segmented accumulation over dst-sorted edges, NODE-ALIGNED wave ranges.
// VGPR accumulator: each lane holds float acc[5][5] (its channel's full
// 25-slot tile) in registers. Per edge: branchless row/col weight vectors
// (2 cndmask each) + 5 mul + 25 fma. NO LDS, no DS ops, no mem-carried dep.
// I<64: 64/I edges processed concurrently by lane groups; merged at node
// flush with __shfl_xor trees. Flush: bf16 stores of [acc*1/deg | hin | 0].
// ===========================================================================
template<int I, int KP>
__global__ __launch_bounds__(256) void seg_accum_kernel(
        const unsigned short* __restrict__ xb, const int4* __restrict__ rec,
        const int* __restrict__ off, unsigned short* __restrict__ accB,
        int nlo, int nhi) {
    constexpr int SLOTS = KKSLOTS * I;
    constexpr int EPW = 64 / I;
    int wline = threadIdx.x >> 6, lane = threadIdx.x & 63;
    int wid = blockIdx.x * 4 + wline;
    int nwt = gridDim.x << 2;

    int e_lo = (nlo == 0) ? 0 : off[nlo - 1];
    int e_hi = off[nhi - 1];
    long long span = (long long)e_hi - e_lo;
    int t0 = e_lo + (int)(span * wid / nwt);
    int t1 = e_lo + (int)(span * (wid + 1) / nwt);

    int ns, ne;
    {   int lo = nlo, hi = nhi;
        while (lo < hi) { int m = (lo + hi) >> 1; if (off[m] > t0) hi = m; else lo = m + 1; }
        ns = (wid == 0) ? nlo : lo; }
    {   int lo = nlo, hi = nhi;
        while (lo < hi) { int m = (lo + hi) >> 1; if (off[m] > t1) hi = m; else lo = m + 1; }
        ne = (wid == nwt - 1) ? nhi : lo; }
    if (ns >= ne) return;

    int h  = lane / I;            // edge sub-index within wave
    int ch = lane % I;            // channel

    float acc[5][5];
    #pragma unroll
    for (int r = 0; r < 5; ++r)
        #pragma unroll
        for (int c = 0; c < 5; ++c) acc[r][c] = 0.0f;

    int j = (ns == 0) ? 0 : off[ns - 1];
    for (int n = ns; n < ne; ++n) {
        int je = off[n];
        int jstart = j;
        for (; j < je; j += EPW) {
            int idx = j + h;
            int cl = min(idx, je - 1);
            int4 r = rec[cl];
            float scale = (idx < je) ? 1.0f : 0.0f;
            float f0 = __int_as_float(r.z), f1 = __int_as_float(r.w);
            float g0 = 1.0f - f0, g1 = 1.0f - f1;
            int i0 = r.y & 0xFF, i1 = (r.y >> 8) & 0xFF;
            float xv = bf2f(xb[(size_t)r.x * I + ch]) * scale;
            float w1v[5], p0[5];
            #pragma unroll
            for (int c = 0; c < 5; ++c)
                w1v[c] = (c == i1) ? g1 : ((c == i1 + 1) ? f1 : 0.0f);
            #pragma unroll
            for (int rr = 0; rr < 5; ++rr)
                p0[rr] = ((rr == i0) ? g0 : ((rr == i0 + 1) ? f0 : 0.0f)) * xv;
            #pragma unroll
            for (int rr = 0; rr < 5; ++rr)
                #pragma unroll
                for (int c = 0; c < 5; ++c)
                    acc[rr][c] = fmaf(p0[rr], w1v[c], acc[rr][c]);
        }
        j = je;

        // flush node n: merge lane groups, scale by 1/deg, store bf16
        float dinv = 1.0f / fmaxf((float)(je - jstart), 1.0f);
        unsigned short* drow = accB + (size_t)(n - nlo) * KP;
        #pragma unroll
        for (int rr = 0; rr < 5; ++rr) {
            #pragma unroll
            for (int c = 0; c < 5; ++c) {
                float v = acc[rr][c];
                if constexpr (EPW > 1) {
                    #pragma unroll
                    for (int s = I; s < 64; s <<= 1) v += __shfl_xor(v, s, 64);
                }
                if (lane < I) drow[(rr * 5 + c) * I + ch] = f2bf(v * dinv);
                acc[rr][c] = 0.0f;
            }
        }
        if (lane < I) drow[SLOTS + ch] = xb[(size_t)n * I + ch];
        if constexpr (KP > SLOTS + I) {
            if (lane < KP - SLOTS - I) drow[SLOTS + I + lane] = 0;
        }
    }
}

// ===========================================================================
// MFMA contraction: hout[n][o] = ELU( accB[n][:] . WT[o][:] + bias[o] )
// Block: 256 threads = 4 waves; wave = 16 nodes; LDS-staged WT tile.
// mfma_f32_16x16x32_bf16; C/D: col=lane&15, row=quad*4+reg.
// ===========================================================================
template<int KP, int O, int OP>
__global__ __launch_bounds__(256) void contract_mfma_kernel(
        const unsigned short* __restrict__ accB, const unsigned short* __restrict__ WT,
        const float* __restrict__ bias, unsigned short* __restrict__ hout,
        int nlo, int nhi) {
    constexpr int NF = OP / 16;
    constexpr int LDW = 40;                    // padded LDS row stride (bf16 units)
    __shared__ unsigned short wTl[OP][LDW];
    int tid = threadIdx.x;
    int wv = tid >> 6, lane = tid & 63;
    int quad = lane >> 4, l16 = lane & 15;
    int n0 = nlo + blockIdx.x * 64;

    int an = n0 + wv * 16 + l16;               // node for A-operand
    int arow = min(an, nhi - 1) - nlo;

    f32x4 acc[NF];
    #pragma unroll
    for (int t = 0; t < NF; ++t) acc[t] = (f32x4){0.0f, 0.0f, 0.0f, 0.0f};

    for (int k0 = 0; k0 < KP; k0 += 32) {
        for (int t = tid; t < OP * 8; t += 256) {
            int o = t >> 3;
            int kk = (t & 7) * 4;
            *(us4*)&wTl[o][kk] = *(const us4*)&WT[(size_t)o * KP + k0 + kk];
        }
        __syncthreads();
        short8 a = *(const short8*)(accB + (size_t)arow * KP + k0 + quad * 8);
        #pragma unroll
        for (int t = 0; t < NF; ++t) {
            short8 b = *(const short8*)&wTl[t * 16 + l16][quad * 8];
            acc[t] = __builtin_amdgcn_mfma_f32_16x16x32_bf16(a, b, acc[t], 0, 0, 0);
        }
        __syncthreads();
    }

    #pragma unroll
    for (int t = 0; t < NF; ++t) {
        int o = t * 16 + l16;
        if (o >= O) continue;
        float bs = bias[o];
        #pragma unroll
        for (int r = 0; r < 4; ++r) {
            int n = n0 + wv * 16 + quad * 4 + r;
            if (n >= nhi) continue;
            float v = acc[t][r] + bs;
            v = (v > 0.0f) ? v : expm1f(v);
            hout[(size_t)n * O + o] = f2bf(v);
        }
    }
}

// ===========================================================================
// segmented graph sum (batch sorted, h3 bf16) + fused count + head
// ===========================================================================
#define GS_CH 128
__global__ __launch_bounds__(128) void graph_reduce_kernel(
        const unsigned short* __restrict__ h3, const int* __restrict__ batch,
        float* __restrict__ g, float* __restrict__ cnt, int N) {
    int o = threadIdx.x;
    int n0 = blockIdx.x * GS_CH;
    int n1 = min(n0 + GS_CH, N);
    if (o < 124) {
        float local = 0.0f;
        int cur_b = batch[n0];
        for (int n = n0; n < n1; ++n) {
            int b = batch[n];
            if (b != cur_b) {
                atomicAdd(&g[cur_b * 124 + o], local);
                local = 0.0f;
                cur_b = b;
            }
            local += bf2f(h3[(size_t)n * 124 + o]);
        }
        atomicAdd(&g[cur_b * 124 + o], local);
    } else if (o == 124) {
        float localc = 0.0f;
        int cur_b = batch[n0];
        for (int n = n0; n < n1; ++n) {
            int b = batch[n];
            if (b != cur_b) {
                atomicAdd(&cnt[cur_b], localc);
                localc = 0.0f;
                cur_b = b;
            }
            localc += 1.0f;
        }
        atomicAdd(&cnt[cur_b], localc);
    }
}

__global__ void head_kernel(const float* __restrict__ g, const float* __restrict__ cnt,
                            const float* __restrict__ fcw, const float* __restrict__ fcb,
                            float* __restrict__ out) {
    __shared__ float logits[32];
    __shared__ float red[2];
    int b = blockIdx.x;
    int o = threadIdx.x;
    float c = fmaxf(cnt[b], 1.0f);
    if (o < 30) {
        float a = fcb[o];
        for (int i = 0; i < 124; ++i)
            a = fmaf(g[b * 124 + i] / c, fcw[i * 30 + o], a);
        logits[o] = a;
    }
    __syncthreads();
    if (o == 0) {
        float m = -1e30f;
        for (int j = 0; j < 30; ++j) m = fmaxf(m, logits[j]);
        float s = 0.0f;
        for (int j = 0; j < 30; ++j) s += expf(logits[j] - m);
        red[0] = m;
        red[1] = logf(s);
    }
    __syncthreads();
    if (o < 30) out[b * 30 + o] = logits[o] - red[0] - red[1];
}

// ---------------------------------------------------------------------------
// per-layer driver (node-chunked so acc fits whatever ws_size allows)
// ---------------------------------------------------------------------------
template<int I, int O, int OP>
static void run_layer(const unsigned short* hb, const unsigned short* WT, const float* bias,
                      unsigned short* hout, unsigned short* accB,
                      const int4* rec, const int* off,
                      int N, size_t avail, hipStream_t stream) {
    constexpr int KP = ((26 * I + 31) / 32) * 32;
    size_t perNode = (size_t)KP * 2;
    size_t maxNodesS = avail / perNode;
    int maxNodes = (maxNodesS > (size_t)N) ? N : (int)maxNodesS;
    if (maxNodes < 64) maxNodes = 64;
    for (int nlo = 0; nlo < N; nlo += maxNodes) {
        int nhi = nlo + maxNodes;
        if (nhi > N) nhi = N;
        int cn = nhi - nlo;
        seg_accum_kernel<I, KP><<<2048, 256, 0, stream>>>(hb, rec, off, accB, nlo, nhi);
        contract_mfma_kernel<KP, O, OP><<<(cn + 63) / 64, 256, 0, stream>>>(
            accB, WT, bias, hout, nlo, nhi);
    }
}

extern "C" void kernel_launch(void* const* d_in, const int* in_sizes, int n_in,
                              void* d_out, int out_size, void* d_ws, size_t ws_size,
                              hipStream_t stream) {
    const float* x      = (const float*)d_in[0];
    const int*   ei     = (const int*)  d_in[1];
    const float* pseudo = (const float*)d_in[2];
    const int*   batch  = (const int*)  d_in[3];
    const float* W1 = (const float*)d_in[4];
    const float* r1 = (const float*)d_in[5];
    const float* b1 = (const float*)d_in[6];
    const float* W2 = (const float*)d_in[7];
    const float* r2 = (const float*)d_in[8];
    const float* b2 = (const float*)d_in[9];
    const float* W3 = (const float*)d_in[10];
    const float* r3 = (const float*)d_in[11];
    const float* b3 = (const float*)d_in[12];
    const float* fcw = (const float*)d_in[13];
    const float* fcb = (const float*)d_in[14];

    int N = in_sizes[0] / 8;
    int E = in_sizes[1] / 2;
    const int* srcp = ei;
    const int* dstp = ei + E;

    constexpr int KP1 = 224, KP2 = 832, KP3 = 1664;

    // workspace carve (all pieces 16B-multiple)
    char* p = (char*)d_ws;
    unsigned short* xb  = (unsigned short*)p; p += (size_t)N * 8 * 2;
    unsigned short* h1  = (unsigned short*)p; p += (size_t)N * 32 * 2;
    unsigned short* h2  = (unsigned short*)p; p += (size_t)N * 64 * 2;
    unsigned short* h3  = (unsigned short*)p; p += (size_t)N * 124 * 2;
    float* gbuf = (float*)p; p += 64 * 124 * 4;
    float* cntF = (float*)p; p += 256;
    int*   cntI = (int*)p;   p += ((size_t)N * 4 + 15) & ~15ULL;
    int*   off  = (int*)p;   p += ((size_t)N * 4 + 15) & ~15ULL;
    int*   bsum = (int*)p;   p += SCAN_B * 4;
    int4*  rec  = (int4*)p;  p += (size_t)E * 16;
    unsigned short* WT1 = (unsigned short*)p; p += (size_t)32  * KP1 * 2;
    unsigned short* WT2 = (unsigned short*)p; p += (size_t)64  * KP2 * 2;
    unsigned short* WT3 = (unsigned short*)p; p += (size_t)128 * KP3 * 2;
    unsigned short* accB = (unsigned short*)p;
    size_t used = (size_t)(p - (char*)d_ws);
    size_t avail = (ws_size > used) ? (ws_size - used) : 0;

    // zero: gbuf + cntF + cntI (contiguous)
    hipMemsetAsync(gbuf, 0, 64 * 124 * 4 + 256 + (((size_t)N * 4 + 15) & ~15ULL), stream);

    // CSR build
    int nb_scan = (N + SCAN_B - 1) / SCAN_B;
    csr_count_kernel<<<(E + 255) / 256, 256, 0, stream>>>(dstp, cntI, E);
    scan1_kernel<<<nb_scan, SCAN_B, 0, stream>>>(cntI, off, bsum, N);
    scan2_kernel<<<1, SCAN_B, 0, stream>>>(bsum, nb_scan);
    scan3_kernel<<<nb_scan, SCAN_B, 0, stream>>>(off, bsum, N);
    csr_fill_kernel<<<(E + 255) / 256, 256, 0, stream>>>(srcp, dstp, pseudo, off, rec, E);

    // conversions / weight prep
    to_bf16_kernel<<<(N * 8 + 255) / 256, 256, 0, stream>>>(x, xb, N * 8);
    build_wt_kernel<KP1, 8,  32,  32 ><<<(32  * KP1 + 255) / 256, 256, 0, stream>>>(W1, r1, WT1);
    build_wt_kernel<KP2, 32, 64,  64 ><<<(64  * KP2 + 255) / 256, 256, 0, stream>>>(W2, r2, WT2);
    build_wt_kernel<KP3, 64, 124, 128><<<(128 * KP3 + 255) / 256, 256, 0, stream>>>(W3, r3, WT3);

    run_layer<8,  32,  32 >(xb, WT1, b1, h1, accB, rec, off, N, avail, stream);
    run_layer<32, 64,  64 >(h1, WT2, b2, h2, accB, rec, off, N, avail, stream);
    run_layer<64, 124, 128>(h2, WT3, b3, h3, accB, rec, off, N, avail, stream);

    graph_reduce_kernel<<<(N + GS_CH - 1) / GS_CH, 128, 0, stream>>>(h3, batch, gbuf, cntF, N);
    head_kernel<<<64, 64, 0, stream>>>(gbuf, cntF, fcw, fcb, (float*)d_out);
}